// Round 7
// baseline (208.343 us; speedup 1.0000x reference)
//
#include <hip/hip_runtime.h>
#include <hip/hip_bf16.h>

#define N_TOT 16384
#define B_HALF 8192
#define D 256
#define NGRAN 32                          // 16B granules per row (D/8)
#define BN 64                             // cols per tile
#define NSPLIT 8
#define COLS_PER_SPLIT (N_TOT / NSPLIT)   // 2048
#define NTILES (COLS_PER_SPLIT / BN)      // 32
#define BM 256                            // rows per block = 4 waves * 64

#define LOG2E 1.4426950408889634f
#define LN2   0.6931471805599453f

typedef short bf16x8 __attribute__((ext_vector_type(8)));
typedef float f32x4 __attribute__((ext_vector_type(4)));

__device__ __forceinline__ float fexp2(float x) {
#if __has_builtin(__builtin_amdgcn_exp2f)
    return __builtin_amdgcn_exp2f(x);
#else
    return __expf(x * LN2);
#endif
}

__device__ __forceinline__ ushort f2bf(float x) {
    uint32_t u = __float_as_uint(x);
    uint32_t r = u + 0x7FFFu + ((u >> 16) & 1u);   // RNE; inputs finite
    return (ushort)(r >> 16);
}

// ---------------- stage 1: fp32 -> prescaled bf16, TRANSPOSED granule layout --
// zt granule (c, r) at elem offset (c*N_TOT + r)*8 holds z[r][c*8 .. c*8+7] * s
// so zt_i . zt_j = log2-domain logit. Writes fully coalesced.
__global__ void convert_kernel(const float* __restrict__ z1,
                               const float* __restrict__ z2,
                               const float* __restrict__ lsp,
                               ushort* __restrict__ zt) {
    const float scale = fminf(__expf(lsp[0]), 100.0f);
    const float s = __fsqrt_rn(scale * LOG2E);
    int T = blockIdx.x * blockDim.x + threadIdx.x;   // T = c*N_TOT + r
    const int c = T >> 14;                            // /N_TOT
    const int r = T & (N_TOT - 1);
    const int half_elems = B_HALF * D;
    int e = r * D + c * 8;
    const float* src = (e < half_elems) ? (z1 + e) : (z2 + (e - half_elems));
    float4 f0 = *reinterpret_cast<const float4*>(src);
    float4 f1 = *reinterpret_cast<const float4*>(src + 4);
    ushort o[8];
    o[0] = f2bf(f0.x * s); o[1] = f2bf(f0.y * s); o[2] = f2bf(f0.z * s); o[3] = f2bf(f0.w * s);
    o[4] = f2bf(f1.x * s); o[5] = f2bf(f1.y * s); o[6] = f2bf(f1.z * s); o[7] = f2bf(f1.w * s);
    *reinterpret_cast<bf16x8*>(zt + (size_t)T * 8) = *reinterpret_cast<bf16x8*>(o);
}

// ---------------- stage 1b: exact fp32 target logits ----------------
__global__ void target_kernel(const float* __restrict__ z1,
                              const float* __restrict__ z2,
                              const float* __restrict__ lsp,
                              float* __restrict__ tnat) {
    const int r    = blockIdx.x * 4 + (threadIdx.x >> 6);
    const int lane = threadIdx.x & 63;
    const float* zr = (r < B_HALF) ? (z1 + (size_t)r * D) : (z2 + (size_t)(r - B_HALF) * D);
    const float* zp = (r < B_HALF) ? (z2 + (size_t)r * D) : (z1 + (size_t)(r - B_HALF) * D);
    float4 a = *reinterpret_cast<const float4*>(zr + lane * 4);
    float4 b = *reinterpret_cast<const float4*>(zp + lane * 4);
    float d = a.x * b.x + a.y * b.y + a.z * b.z + a.w * b.w;
#pragma unroll
    for (int off = 1; off < 64; off <<= 1) d += __shfl_xor(d, off);
    if (lane == 0) {
        const float scale = fminf(__expf(lsp[0]), 100.0f);
        tnat[r] = scale * d;
    }
}

// ---------------- epilogue helper (branchless online LSE, N-rep=4) ----------
template<bool MASKD>
__device__ __forceinline__ void epilogue(const f32x4 (&acc)[4][4],
                                         float (&m2)[16], float (&l2)[16],
                                         int qrow0, int crow0, int g, int lg) {
#pragma unroll
    for (int mi = 0; mi < 4; ++mi) {
#pragma unroll
        for (int j = 0; j < 4; ++j) {
            const int slot = mi * 4 + j;
            float v0 = acc[mi][0][j], v1 = acc[mi][1][j];
            float v2 = acc[mi][2][j], v3 = acc[mi][3][j];
            if (MASKD) {
                const int r  = qrow0 + mi * 16 + g * 4 + j;
                const int c0 = crow0 + lg;
                if (c0      == r) v0 = -1e30f;
                if (c0 + 16 == r) v1 = -1e30f;
                if (c0 + 32 == r) v2 = -1e30f;
                if (c0 + 48 == r) v3 = -1e30f;
            }
            const float m_old = m2[slot];
            float m_new = fmaxf(fmaxf(fmaxf(v0, v1), fmaxf(v2, v3)), m_old);
            float er = fexp2(m_old - m_new);
            float e0 = fexp2(v0 - m_new);
            float e1 = fexp2(v1 - m_new);
            float e2 = fexp2(v2 - m_new);
            float e3 = fexp2(v3 - m_new);
            l2[slot] = __builtin_fmaf(l2[slot], er, (e0 + e1) + (e2 + e3));
            m2[slot] = m_new;
        }
    }
}

// ------- stage 2: flash LSE sweep, M-rep=4 x N-rep=4, slim addressing --------
__global__ __launch_bounds__(256)
__attribute__((amdgpu_waves_per_eu(2, 2)))
void infonce_main(const ushort* __restrict__ zt,
                  float* __restrict__ part) {
    // B tile: [granule c 0..31][colrow 0..63], 16B entries, double-buffered
    __shared__ ushort ks[2][BN * NGRAN * 8];   // 2 x 32 KB, linear

    const int tid  = threadIdx.x;
    const int wid  = tid >> 6;
    const int lane = tid & 63;
    const int g    = lane >> 4;     // 0..3
    const int lg   = lane & 15;     // 0..15
    const int qrow0   = blockIdx.x * BM + wid * 64;
    const int split   = blockIdx.y;
    const int colbase = split * COLS_PER_SPLIT;

    // A fragments: 4 M-frags x 8 K-frags, register-resident (128 regs)
    bf16x8 afrag[4][8];
#pragma unroll
    for (int kk = 0; kk < 8; ++kk)
#pragma unroll
        for (int mi = 0; mi < 4; ++mi)
            afrag[mi][kk] = *reinterpret_cast<const bf16x8*>(
                zt + ((size_t)(kk * 4 + g) * N_TOT + qrow0 + mi * 16 + lg) * 8);

    float m2[16], l2[16];
#pragma unroll
    for (int s = 0; s < 16; ++s) { m2[s] = -1e30f; l2[s] = 0.0f; }

    // staging: chunk = it*256 + tid; granule c = it*4 + wid; colrow = lane.
    // each instr: 64 lanes x 16B = contiguous 1KB from zt, linear LDS dest.
    const ushort* srcB0 = zt + ((size_t)wid * N_TOT + lane) * 8;

#define STAGE(buf, t)                                                               \
    {                                                                               \
        const ushort* srcT = srcB0 + (size_t)(colbase + (t) * BN) * 8;              \
        _Pragma("unroll")                                                           \
        for (int it = 0; it < 8; ++it)                                              \
            __builtin_amdgcn_global_load_lds(                                       \
                (const __attribute__((address_space(1))) void*)(srcT + (size_t)it * 4 * N_TOT * 8), \
                (__attribute__((address_space(3))) void*)&ks[buf][(it * 4 + wid) * 512], \
                16, 0, 0);                                                          \
    }

    // per-lane B-read base pointer; all reads are base + compile-time imm
    const char* kb0 = (const char*)(&ks[0][0]) + g * 1024 + lg * 16;

    STAGE(0, 0);
    __syncthreads();
    int cur = 0;

    for (int t = 0; t < NTILES; ++t) {
        if (t + 1 < NTILES) STAGE(cur ^ 1, t + 1);   // prefetch next tile

        f32x4 acc[4][4];
#pragma unroll
        for (int mi = 0; mi < 4; ++mi)
#pragma unroll
            for (int n = 0; n < 4; ++n) acc[mi][n] = (f32x4){0.f, 0.f, 0.f, 0.f};

        const char* kb = kb0 + (cur << 15);   // buffer select
#pragma unroll
        for (int kk = 0; kk < 8; ++kk) {
#pragma unroll
            for (int n = 0; n < 4; ++n) {
                // entry (kk*4+g)*64 + n*16 + lg  -> byte kk*4096 + n*256 (+lane base)
                bf16x8 b = *reinterpret_cast<const bf16x8*>(kb + kk * 4096 + n * 256);
                acc[0][n] = __builtin_amdgcn_mfma_f32_16x16x32_bf16(afrag[0][kk], b, acc[0][n], 0, 0, 0);
                acc[1][n] = __builtin_amdgcn_mfma_f32_16x16x32_bf16(afrag[1][kk], b, acc[1][n], 0, 0, 0);
                acc[2][n] = __builtin_amdgcn_mfma_f32_16x16x32_bf16(afrag[2][kk], b, acc[2][n], 0, 0, 0);
                acc[3][n] = __builtin_amdgcn_mfma_f32_16x16x32_bf16(afrag[3][kk], b, acc[3][n], 0, 0, 0);
            }
        }

        const int crow0 = colbase + t * BN;
        if (crow0 == qrow0)   // diagonal tile (wave rows == tile cols)
            epilogue<true >(acc, m2, l2, qrow0, crow0, g, lg);
        else
            epilogue<false>(acc, m2, l2, qrow0, crow0, g, lg);

        __syncthreads();      // drains prefetch + all waves done with ks[cur]
        cur ^= 1;
    }
#undef STAGE

    // merge (m,l) across the 16-lane column group
#pragma unroll
    for (int s = 0; s < 16; ++s) {
        float m = m2[s], l = l2[s];
#pragma unroll
        for (int off = 1; off < 16; off <<= 1) {
            float mo = __shfl_xor(m, off);
            float lo = __shfl_xor(l, off);
            float mm = fmaxf(m, mo);
            l = l * fexp2(m - mm) + lo * fexp2(mo - mm);
            m = mm;
        }
        m2[s] = m; l2[s] = l;
    }
    if (lg == 0) {
#pragma unroll
        for (int mi = 0; mi < 4; ++mi)
#pragma unroll
            for (int j = 0; j < 4; ++j) {
                int r = qrow0 + mi * 16 + g * 4 + j;
                int s = mi * 4 + j;
                float* p = part + (size_t)(r * NSPLIT + split) * 2;
                p[0] = m2[s]; p[1] = l2[s];
            }
    }
}

// ---------------- stage 3: per-row combine + deterministic sum ----------------
__global__ void reduce_kernel(const float* __restrict__ part,
                              const float* __restrict__ tnat,
                              float* __restrict__ bsum) {
    int r = blockIdx.x * 256 + threadIdx.x;
    float m = -1e30f, l = 0.f;
#pragma unroll
    for (int s = 0; s < NSPLIT; ++s) {
        const float* p = part + (size_t)(r * NSPLIT + s) * 2;
        float ms = p[0], lv = p[1];
        float mm = fmaxf(m, ms);
        l = l * fexp2(m - mm) + lv * fexp2(ms - mm);
        m = mm;
    }
    float v = LN2 * (m + __log2f(l)) - tnat[r];   // nll for this row
#pragma unroll
    for (int off = 1; off < 64; off <<= 1) v += __shfl_xor(v, off);
    __shared__ float ws4[4];
    int lane = threadIdx.x & 63, wid = threadIdx.x >> 6;
    if (lane == 0) ws4[wid] = v;
    __syncthreads();
    if (threadIdx.x == 0)
        bsum[blockIdx.x] = ws4[0] + ws4[1] + ws4[2] + ws4[3];
}

__global__ void final_kernel(const float* __restrict__ bsum,
                             float* __restrict__ out) {
    float v = bsum[threadIdx.x];   // 64 threads, 64 block sums
#pragma unroll
    for (int off = 1; off < 64; off <<= 1) v += __shfl_xor(v, off);
    if (threadIdx.x == 0) out[0] = v * (1.0f / (float)N_TOT);
}

extern "C" void kernel_launch(void* const* d_in, const int* in_sizes, int n_in,
                              void* d_out, int out_size, void* d_ws, size_t ws_size,
                              hipStream_t stream) {
    const float* z1 = (const float*)d_in[0];
    const float* z2 = (const float*)d_in[1];
    const float* ls = (const float*)d_in[2];
    float* out = (float*)d_out;

    ushort* zt   = (ushort*)d_ws;                                        // 8 MB
    float*  part = (float*)((char*)d_ws + (size_t)N_TOT * D * 2);        // 1 MB
    float*  tnat = (float*)((char*)part + (size_t)N_TOT * NSPLIT * 2 * sizeof(float));
    float*  bsum = (float*)((char*)tnat + (size_t)N_TOT * sizeof(float));

    convert_kernel<<<(N_TOT * NGRAN) / 256, 256, 0, stream>>>(z1, z2, ls, zt);
    target_kernel<<<N_TOT / 4, 256, 0, stream>>>(z1, z2, ls, tnat);
    dim3 grid(N_TOT / BM, NSPLIT);
    infonce_main<<<grid, 256, 0, stream>>>(zt, part);
    reduce_kernel<<<N_TOT / 256, 256, 0, stream>>>(part, tnat, bsum);
    final_kernel<<<1, 64, 0, stream>>>(bsum, out);
}

// Round 8
// 158.381 us; speedup vs baseline: 1.3155x; 1.3155x over previous
//
#include <hip/hip_runtime.h>
#include <hip/hip_bf16.h>

#define N_TOT 16384
#define B_HALF 8192
#define D 256
#define NGRAN 32                          // 16B granules per row (D/8)
#define BN 32                             // cols per wave-private tile
#define NSPLIT 8
#define COLS_PER_SPLIT (N_TOT / NSPLIT)   // 2048
#define NTILES (COLS_PER_SPLIT / BN)      // 64
#define NWAVE 8
#define BM (NWAVE * 64)                   // 512 rows per block

#define LOG2E 1.4426950408889634f
#define LN2   0.6931471805599453f

typedef short bf16x8 __attribute__((ext_vector_type(8)));
typedef float f32x4 __attribute__((ext_vector_type(4)));

__device__ __forceinline__ float fexp2(float x) {
#if __has_builtin(__builtin_amdgcn_exp2f)
    return __builtin_amdgcn_exp2f(x);
#else
    return __expf(x * LN2);
#endif
}

__device__ __forceinline__ ushort f2bf(float x) {
    uint32_t u = __float_as_uint(x);
    uint32_t r = u + 0x7FFFu + ((u >> 16) & 1u);   // RNE; inputs finite
    return (ushort)(r >> 16);
}

// ---------------- stage 1: fp32 -> prescaled bf16, TRANSPOSED granule layout --
// zt granule (c, r) at elem offset (c*N_TOT + r)*8 holds z[r][c*8 .. c*8+7] * s
// so zt_i . zt_j = log2-domain logit. Writes fully coalesced.
__global__ void convert_kernel(const float* __restrict__ z1,
                               const float* __restrict__ z2,
                               const float* __restrict__ lsp,
                               ushort* __restrict__ zt) {
    const float scale = fminf(__expf(lsp[0]), 100.0f);
    const float s = __fsqrt_rn(scale * LOG2E);
    int T = blockIdx.x * blockDim.x + threadIdx.x;   // T = c*N_TOT + r
    const int c = T >> 14;                            // /N_TOT
    const int r = T & (N_TOT - 1);
    const int half_elems = B_HALF * D;
    int e = r * D + c * 8;
    const float* src = (e < half_elems) ? (z1 + e) : (z2 + (e - half_elems));
    float4 f0 = *reinterpret_cast<const float4*>(src);
    float4 f1 = *reinterpret_cast<const float4*>(src + 4);
    ushort o[8];
    o[0] = f2bf(f0.x * s); o[1] = f2bf(f0.y * s); o[2] = f2bf(f0.z * s); o[3] = f2bf(f0.w * s);
    o[4] = f2bf(f1.x * s); o[5] = f2bf(f1.y * s); o[6] = f2bf(f1.z * s); o[7] = f2bf(f1.w * s);
    *reinterpret_cast<bf16x8*>(zt + (size_t)T * 8) = *reinterpret_cast<bf16x8*>(o);
}

// ---------------- stage 1b: exact fp32 target logits ----------------
__global__ void target_kernel(const float* __restrict__ z1,
                              const float* __restrict__ z2,
                              const float* __restrict__ lsp,
                              float* __restrict__ tnat) {
    const int r    = blockIdx.x * 4 + (threadIdx.x >> 6);
    const int lane = threadIdx.x & 63;
    const float* zr = (r < B_HALF) ? (z1 + (size_t)r * D) : (z2 + (size_t)(r - B_HALF) * D);
    const float* zp = (r < B_HALF) ? (z2 + (size_t)r * D) : (z1 + (size_t)(r - B_HALF) * D);
    float4 a = *reinterpret_cast<const float4*>(zr + lane * 4);
    float4 b = *reinterpret_cast<const float4*>(zp + lane * 4);
    float d = a.x * b.x + a.y * b.y + a.z * b.z + a.w * b.w;
#pragma unroll
    for (int off = 1; off < 64; off <<= 1) d += __shfl_xor(d, off);
    if (lane == 0) {
        const float scale = fminf(__expf(lsp[0]), 100.0f);
        tnat[r] = scale * d;
    }
}

// ---------------- epilogue helper (branchless online LSE, N-rep=2) ----------
template<bool MASKD>
__device__ __forceinline__ void epilogue(const f32x4 (&acc)[4][2],
                                         float (&m2)[16], float (&l2)[16],
                                         int qrow0, int crow0, int g, int lg) {
#pragma unroll
    for (int mi = 0; mi < 4; ++mi) {
#pragma unroll
        for (int j = 0; j < 4; ++j) {
            const int slot = mi * 4 + j;
            float v0 = acc[mi][0][j], v1 = acc[mi][1][j];
            if (MASKD) {
                const int r  = qrow0 + mi * 16 + g * 4 + j;
                const int c0 = crow0 + lg;
                if (c0      == r) v0 = -1e30f;
                if (c0 + 16 == r) v1 = -1e30f;
            }
            const float m_old = m2[slot];
            float m_new = fmaxf(fmaxf(v0, v1), m_old);
            float er = fexp2(m_old - m_new);
            float e0 = fexp2(v0 - m_new);
            float e1 = fexp2(v1 - m_new);
            l2[slot] = __builtin_fmaf(l2[slot], er, e0 + e1);
            m2[slot] = m_new;
        }
    }
}

// ------- stage 2: barrier-free flash LSE sweep, wave-private B tiles --------
__global__ __launch_bounds__(512)
__attribute__((amdgpu_waves_per_eu(2, 2)))
void infonce_main(const ushort* __restrict__ zt,
                  float* __restrict__ part) {
    // per-wave private B tile: [granule c 0..31][col 0..31], 16B entries
    __shared__ ushort ks[NWAVE][BN * NGRAN * 8];   // 8 x 16 KB = 128 KB

    const int tid  = threadIdx.x;
    const int wid  = tid >> 6;
    const int lane = tid & 63;
    const int g    = lane >> 4;     // 0..3
    const int lg   = lane & 15;     // 0..15
    const int qrow0   = blockIdx.y * BM + wid * 64;
    const int split   = blockIdx.x;                 // grid.x=8 -> XCD = split
    const int colbase = split * COLS_PER_SPLIT;

    // A fragments: 4 M-frags x 8 K-frags, register-resident (128 regs -> accum)
    bf16x8 afrag[4][8];
#pragma unroll
    for (int kk = 0; kk < 8; ++kk)
#pragma unroll
        for (int mi = 0; mi < 4; ++mi)
            afrag[mi][kk] = *reinterpret_cast<const bf16x8*>(
                zt + ((size_t)(kk * 4 + g) * N_TOT + qrow0 + mi * 16 + lg) * 8);

    float m2[16], l2[16];
#pragma unroll
    for (int s = 0; s < 16; ++s) { m2[s] = -1e30f; l2[s] = 0.0f; }

    // private staging: chunk = it*64 + lane; granule c = it*2 + (lane>>5);
    // col r = lane&31. each instr: 64 lanes x 16B -> two 512B runs from zt.
    const ushort* srcW = zt + ((size_t)(lane >> 5) * N_TOT + (lane & 31)) * 8;

#define STAGE(t)                                                                     \
    {                                                                                \
        const ushort* s_ = srcW + (size_t)(colbase + (t) * BN) * 8;                  \
        _Pragma("unroll")                                                            \
        for (int it = 0; it < 16; ++it)                                              \
            __builtin_amdgcn_global_load_lds(                                        \
                (const __attribute__((address_space(1))) void*)(s_ + (size_t)it * 2 * N_TOT * 8), \
                (__attribute__((address_space(3))) void*)&ks[wid][it * 512],         \
                16, 0, 0);                                                           \
    }

    // anti-phase SIMD partner waves (wid and wid^4 share a SIMD):
    if (wid & 4) __builtin_amdgcn_s_sleep(19);   // ~1216 cyc, ~half a tile phase

    STAGE(0);

    // per-lane B-read base; reads are base + compile-time imm offsets
    const char* kb = (const char*)(&ks[wid][0]) + g * 512 + lg * 16;

    for (int t = 0; t < NTILES; ++t) {
        asm volatile("s_waitcnt vmcnt(0)" ::: "memory");   // own stage landed
        __builtin_amdgcn_sched_barrier(0);

        f32x4 acc[4][2];
#pragma unroll
        for (int mi = 0; mi < 4; ++mi)
#pragma unroll
            for (int n = 0; n < 2; ++n) acc[mi][n] = (f32x4){0.f, 0.f, 0.f, 0.f};

#pragma unroll
        for (int kk = 0; kk < 8; ++kk) {
#pragma unroll
            for (int n = 0; n < 2; ++n) {
                bf16x8 b = *reinterpret_cast<const bf16x8*>(kb + kk * 2048 + n * 256);
                acc[0][n] = __builtin_amdgcn_mfma_f32_16x16x32_bf16(afrag[0][kk], b, acc[0][n], 0, 0, 0);
                acc[1][n] = __builtin_amdgcn_mfma_f32_16x16x32_bf16(afrag[1][kk], b, acc[1][n], 0, 0, 0);
                acc[2][n] = __builtin_amdgcn_mfma_f32_16x16x32_bf16(afrag[2][kk], b, acc[2][n], 0, 0, 0);
                acc[3][n] = __builtin_amdgcn_mfma_f32_16x16x32_bf16(afrag[3][kk], b, acc[3][n], 0, 0, 0);
            }
        }

        // all private ds_reads done -> safe to overwrite own tile
        asm volatile("s_waitcnt lgkmcnt(0)" ::: "memory");
        __builtin_amdgcn_sched_barrier(0);
        if (t + 1 < NTILES) STAGE(t + 1);   // latency hidden under epilogue

        const int crow0 = colbase + t * BN;
        if ((crow0 >> 6) == (qrow0 >> 6))   // 32-col tile inside wave's 64-row block
            epilogue<true >(acc, m2, l2, qrow0, crow0, g, lg);
        else
            epilogue<false>(acc, m2, l2, qrow0, crow0, g, lg);
    }
#undef STAGE

    // merge (m,l) across the 16-lane column group
#pragma unroll
    for (int s = 0; s < 16; ++s) {
        float m = m2[s], l = l2[s];
#pragma unroll
        for (int off = 1; off < 16; off <<= 1) {
            float mo = __shfl_xor(m, off);
            float lo = __shfl_xor(l, off);
            float mm = fmaxf(m, mo);
            l = l * fexp2(m - mm) + lo * fexp2(mo - mm);
            m = mm;
        }
        m2[s] = m; l2[s] = l;
    }
    if (lg == 0) {
#pragma unroll
        for (int mi = 0; mi < 4; ++mi)
#pragma unroll
            for (int j = 0; j < 4; ++j) {
                int r = qrow0 + mi * 16 + g * 4 + j;
                int s = mi * 4 + j;
                float* p = part + (size_t)(r * NSPLIT + split) * 2;
                p[0] = m2[s]; p[1] = l2[s];
            }
    }
}

// ---------------- stage 3: per-row combine + deterministic sum ----------------
__global__ void reduce_kernel(const float* __restrict__ part,
                              const float* __restrict__ tnat,
                              float* __restrict__ bsum) {
    int r = blockIdx.x * 256 + threadIdx.x;
    float m = -1e30f, l = 0.f;
#pragma unroll
    for (int s = 0; s < NSPLIT; ++s) {
        const float* p = part + (size_t)(r * NSPLIT + s) * 2;
        float ms = p[0], lv = p[1];
        float mm = fmaxf(m, ms);
        l = l * fexp2(m - mm) + lv * fexp2(ms - mm);
        m = mm;
    }
    float v = LN2 * (m + __log2f(l)) - tnat[r];   // nll for this row
#pragma unroll
    for (int off = 1; off < 64; off <<= 1) v += __shfl_xor(v, off);
    __shared__ float ws4[4];
    int lane = threadIdx.x & 63, wid = threadIdx.x >> 6;
    if (lane == 0) ws4[wid] = v;
    __syncthreads();
    if (threadIdx.x == 0)
        bsum[blockIdx.x] = ws4[0] + ws4[1] + ws4[2] + ws4[3];
}

__global__ void final_kernel(const float* __restrict__ bsum,
                             float* __restrict__ out) {
    float v = bsum[threadIdx.x];   // 64 threads, 64 block sums
#pragma unroll
    for (int off = 1; off < 64; off <<= 1) v += __shfl_xor(v, off);
    if (threadIdx.x == 0) out[0] = v * (1.0f / (float)N_TOT);
}

extern "C" void kernel_launch(void* const* d_in, const int* in_sizes, int n_in,
                              void* d_out, int out_size, void* d_ws, size_t ws_size,
                              hipStream_t stream) {
    const float* z1 = (const float*)d_in[0];
    const float* z2 = (const float*)d_in[1];
    const float* ls = (const float*)d_in[2];
    float* out = (float*)d_out;

    ushort* zt   = (ushort*)d_ws;                                        // 8 MB
    float*  part = (float*)((char*)d_ws + (size_t)N_TOT * D * 2);        // 1 MB
    float*  tnat = (float*)((char*)part + (size_t)N_TOT * NSPLIT * 2 * sizeof(float));
    float*  bsum = (float*)((char*)tnat + (size_t)N_TOT * sizeof(float));

    convert_kernel<<<(N_TOT * NGRAN) / 256, 256, 0, stream>>>(z1, z2, ls, zt);
    target_kernel<<<N_TOT / 4, 256, 0, stream>>>(z1, z2, ls, tnat);
    dim3 grid(NSPLIT, N_TOT / BM);   // x=split -> XCD = linear%8 = split
    infonce_main<<<grid, 512, 0, stream>>>(zt, part);
    reduce_kernel<<<N_TOT / 256, 256, 0, stream>>>(part, tnat, bsum);
    final_kernel<<<1, 64, 0, stream>>>(bsum, out);
}